// Round 3
// baseline (823.531 us; speedup 1.0000x reference)
//
#include <hip/hip_runtime.h>

#define NN 100000
#define HH 512
#define GG 512
#define NPACK 1280
#define NSTRIP 80
#define SB 16384               // strip bytes: 16 cols x 512 k x 2B
#define XTROWS (NN + 128)      // pad rows so tail-block xt stores are unguarded (uniform vmcnt)

typedef unsigned short u16;
typedef unsigned int u32;
typedef __bf16 bf16x8 __attribute__((ext_vector_type(8)));
typedef unsigned short u16x8 __attribute__((ext_vector_type(8)));
typedef float f32x4 __attribute__((ext_vector_type(4)));
typedef __attribute__((address_space(1))) void gvoid_t;
typedef __attribute__((address_space(3))) void lvoid_t;

__device__ __forceinline__ u16 f2bf(float f) {
    unsigned u = __float_as_uint(f);
    unsigned r = u + 0x7FFFu + ((u >> 16) & 1u);   // RNE
    return (u16)(r >> 16);
}
__device__ __forceinline__ float bf2f(u16 b) {
    return __uint_as_float(((unsigned)b) << 16);
}

// ---------------- prep: 16-col-strip-blocked + XOR-swizzled W^T bf16 -----------
// packed col n: [0,256)=ga_g_w1 ; [256,768)=ga_n_w ; [768,1280)=g_w1
// WT layout: strip s=n>>4, nl=n&15. byte = s*SB + nl*1024 + ((ck ^ nl)<<4) + k3*2
//   (ck=k>>3, k3=k&7). Linear global_load_lds staging lands this swizzled in LDS;
//   ds_read_b128 fragment reads are then bank-conflict-free (verified 0 in r2).
// bwv[n] = (bias[n], wvec[n]) packed float2 (padded +16 entries for prefetch OOB).
__global__ void k_prep(const float* __restrict__ gw1, const float* __restrict__ gb1,
                       const float* __restrict__ gw2v,
                       const float* __restrict__ nw, const float* __restrict__ nb,
                       const float* __restrict__ aw1, const float* __restrict__ ab1,
                       const float* __restrict__ aw2, const int* __restrict__ batch,
                       u16* __restrict__ WT, float2* __restrict__ bwv,
                       float* __restrict__ out_emb, int* __restrict__ starts) {
    int idx = blockIdx.x * blockDim.x + threadIdx.x;
    int stride = gridDim.x * blockDim.x;
    for (int i = idx; i < NPACK * 512; i += stride) {
        int n = i >> 9, k = i & 511;
        float v;
        if (n < 256)      v = gw1[k * 256 + n];
        else if (n < 768) v = nw[k * 512 + (n - 256)];
        else              v = aw1[k * 512 + (n - 768)];
        int s = n >> 4, nl = n & 15;
        int ck = k >> 3, k3 = k & 7;
        size_t byte = (size_t)s * SB + nl * 1024 + ((size_t)(ck ^ nl) << 4) + k3 * 2;
        *(u16*)((char*)WT + byte) = f2bf(v);
    }
    for (int n = idx; n < NPACK + 16; n += stride) {
        float bi = 0.f, wv = 0.f;
        if (n < 256)      { bi = gb1[n];       wv = gw2v[n]; }
        else if (n < 768) { bi = nb[n - 256];  wv = 0.f; }
        else if (n < NPACK) {
            bi = ab1[n - 768];
            float s = 0.f;
            for (int h = 0; h < 8; ++h) s += aw2[(n - 768) * 8 + h];
            wv = s * 0.125f;
        }
        bwv[n] = make_float2(bi, wv);
    }
    for (int i = idx; i < GG * HH; i += stride) out_emb[i] = 0.f;
    for (int g = idx; g <= GG; g += stride) {
        if (g == GG) { starts[GG] = NN; continue; }
        int lo = 0, hi = NN;
        while (lo < hi) { int mid = (lo + hi) >> 1; if (batch[mid] < g) lo = mid + 1; else hi = mid; }
        starts[g] = lo;
    }
}

// ---------------- fused GEMM, strip-pipelined, 3 blocks/CU ---------------------
// block = 128 rows as 4 waves x 32 rows. 1280 cols as 80 strips of 16.
// Per strip: dbuf 16KB LDS stage (4 global_load_lds/thread), raw s_barrier +
// COUNTED vmcnt. LDS 32KB/block -> 3 blocks/CU (12 waves, 3/SIMD) to hide the
// ds_read->MFMA latency that capped r2 at 24% MfmaUtil with 2 waves/SIMD.
// nt 0-15: gate | nt 16-47: xt (even: stash bf16, odd: ushort2 store -- layout
// identical to r2's j-packed scheme) | nt 48-79: att score.
__global__ __launch_bounds__(256, 3)
void k_gemm(const float* __restrict__ X, const u16* __restrict__ B,
            const float2* __restrict__ bwv,
            const float* __restrict__ gb2, const float* __restrict__ ab2,
            u16* __restrict__ xt, float* __restrict__ gs, float* __restrict__ as_) {
    __shared__ __align__(16) char ldsB[2 * SB];

    const int tid = threadIdx.x;
    const int lane = tid & 63;
    const int w = tid >> 6;                  // wave -> rows [w*32, w*32+32)
    const int m0 = blockIdx.x * 128;
    const int l16 = lane & 15, kq = lane >> 4;

#define STAGE(s, bsel) do {                                                          \
    const char* _src = (const char*)B + (size_t)(s) * SB + tid * 16;                 \
    char* _dst = ldsB + (bsel) * SB + tid * 16;                                      \
    _Pragma("unroll")                                                                \
    for (int _t = 0; _t < 4; ++_t)                                                   \
        __builtin_amdgcn_global_load_lds((gvoid_t*)(_src + _t * 4096),               \
                                         (lvoid_t*)(_dst + _t * 4096), 16, 0, 0);    \
} while (0)

    STAGE(0, 0);   // strip 0 in flight under the A-panel load

    float b2 = gb2[0];
    float bb = 0.f;
#pragma unroll
    for (int h = 0; h < 8; ++h) bb += ab2[h];
    bb *= 0.125f;

    // ---- A panel: 32 rows/wave, fp32 -> bf16 fragments in registers (128 VGPR) ----
    bf16x8 a_reg[2][16];
#pragma unroll
    for (int i = 0; i < 2; ++i) {
        int row = m0 + w * 32 + i * 16 + l16;
        if (row >= NN) row = NN - 1;
        const float* xp = X + (size_t)row * 512 + kq * 8;
#pragma unroll
        for (int kt = 0; kt < 16; ++kt) {
            float4 f0 = *(const float4*)(xp + kt * 32);
            float4 f1 = *(const float4*)(xp + kt * 32 + 4);
            u16x8 u;
            u[0] = f2bf(f0.x); u[1] = f2bf(f0.y); u[2] = f2bf(f0.z); u[3] = f2bf(f0.w);
            u[4] = f2bf(f1.x); u[5] = f2bf(f1.y); u[6] = f2bf(f1.z); u[7] = f2bf(f1.w);
            a_reg[i][kt] = __builtin_bit_cast(bf16x8, u);
        }
    }

    float2 bw = bwv[l16];        // strip 0 bias/wvec

    float s_[2][4];              // shared between gate phase (nt<16) and att phase (nt>=48)
#pragma unroll
    for (int i = 0; i < 2; ++i)
#pragma unroll
        for (int r = 0; r < 4; ++r) s_[i][r] = 0.f;
    u32 stash[4];                // even-xt-strip bf16 halves (2 u16 per u32)

    for (int nt = 0; nt < NSTRIP; ++nt) {
        const int cur = nt & 1;
        if (nt + 1 < NSTRIP) STAGE(nt + 1, cur ^ 1);

        // Counted waits. Outstanding (oldest->newest): STAGE(nt)=4, bw(nt)=1,
        // [stores(nt-1)=8 iff nt-1 was an odd-xt strip], STAGE(nt+1)=4.
        // Drain exactly STAGE(nt); never drain prefetch/stores mid-loop.
        if (nt == NSTRIP - 1)
            asm volatile("s_waitcnt vmcnt(0)" ::: "memory");
        else if (nt >= 18 && nt <= 48 && !(nt & 1))
            asm volatile("s_waitcnt vmcnt(13)" ::: "memory");
        else
            asm volatile("s_waitcnt vmcnt(5)" ::: "memory");
        __builtin_amdgcn_s_barrier();
        __builtin_amdgcn_sched_barrier(0);   // rule #18: no ds_read hoists above barrier

        f32x4 acc[2];
        acc[0] = {0.f, 0.f, 0.f, 0.f};
        acc[1] = {0.f, 0.f, 0.f, 0.f};

        // b-frag: col n = l16, k-chunk ck = kt*4+kq, byte = l16*1024 + ((ck^l16)<<4)
        const char* bbase = ldsB + cur * SB + l16 * 1024;
        __builtin_amdgcn_s_setprio(1);
#pragma unroll
        for (int kt = 0; kt < 16; ++kt) {
            int off = ((kt * 4 + kq) ^ l16) << 4;
            bf16x8 b0 = *(const bf16x8*)(bbase + off);
            acc[0] = __builtin_amdgcn_mfma_f32_16x16x32_bf16(a_reg[0][kt], b0, acc[0], 0, 0, 0);
            acc[1] = __builtin_amdgcn_mfma_f32_16x16x32_bf16(a_reg[1][kt], b0, acc[1], 0, 0, 0);
        }
        __builtin_amdgcn_s_setprio(0);
        __builtin_amdgcn_s_barrier();   // all waves done reading buf[cur] before restage

        float2 bw_next = bwv[(nt + 1) * 16 + l16];   // padded; older than the stores below

        // ---- epilogue. C/D: col = lane&15, row = kq*4 + reg [m89] ----
        if (nt < 16) {
#pragma unroll
            for (int i = 0; i < 2; ++i)
#pragma unroll
                for (int r = 0; r < 4; ++r)
                    s_[i][r] += fmaxf(acc[i][r] + bw.x, 0.f) * bw.y;
            if (nt == 15) {   // gate scores complete: reduce 16 col-lanes, write, reset
#pragma unroll
                for (int i = 0; i < 2; ++i)
#pragma unroll
                    for (int r = 0; r < 4; ++r) {
                        float pg = s_[i][r];
                        pg += __shfl_xor(pg, 1); pg += __shfl_xor(pg, 2);
                        pg += __shfl_xor(pg, 4); pg += __shfl_xor(pg, 8);
                        int rg = m0 + w * 32 + i * 16 + kq * 4 + r;
                        if (l16 == 0 && rg < NN) gs[rg] = pg + b2;
                        s_[i][r] = 0.f;
                    }
            }
        } else if (nt < 48) {
            const int sx = nt - 16;
            if (!(sx & 1)) {      // even: stash bf16 (no stores -> vmcnt unaffected)
#pragma unroll
                for (int i = 0; i < 2; ++i)
#pragma unroll
                    for (int rp = 0; rp < 2; ++rp) {
                        u32 lo = f2bf(fmaxf(acc[i][rp * 2]     + bw.x, 0.f));
                        u32 hi = f2bf(fmaxf(acc[i][rp * 2 + 1] + bw.x, 0.f));
                        stash[i * 2 + rp] = lo | (hi << 16);
                    }
            } else {              // odd: pair with stash -> same ushort2 layout as r2
                const int s2 = sx >> 1;
#pragma unroll
                for (int i = 0; i < 2; ++i)
#pragma unroll
                    for (int r = 0; r < 4; ++r) {
                        int rg = m0 + w * 32 + i * 16 + kq * 4 + r;   // < XTROWS always
                        ushort2 st;
                        st.x = (u16)(stash[i * 2 + (r >> 1)] >> ((r & 1) * 16));
                        st.y = f2bf(fmaxf(acc[i][r] + bw.x, 0.f));
                        *(ushort2*)(xt + (size_t)rg * 512 + s2 * 32 + l16 * 2) = st;
                    }
            }
        } else {
#pragma unroll
            for (int i = 0; i < 2; ++i)
#pragma unroll
                for (int r = 0; r < 4; ++r)
                    s_[i][r] += fmaxf(acc[i][r] + bw.x, 0.f) * bw.y;
        }
        bw = bw_next;
    }
#undef STAGE

    // ---- att scores: reduce over 16 col-lanes, coalesced write, no atomics ----
#pragma unroll
    for (int i = 0; i < 2; ++i)
#pragma unroll
        for (int r = 0; r < 4; ++r) {
            float pa = s_[i][r];
            pa += __shfl_xor(pa, 1); pa += __shfl_xor(pa, 2);
            pa += __shfl_xor(pa, 4); pa += __shfl_xor(pa, 8);
            int rg = m0 + w * 32 + i * 16 + kq * 4 + r;
            if (l16 == 0 && rg < NN) as_[rg] = pa + bb;
        }
}

// ---------------- per-graph segment max + exp-sum (both scores) ----------------
__global__ void k_seg(const float* __restrict__ gs, const float* __restrict__ as_,
                      const int* __restrict__ starts,
                      float* __restrict__ mg, float* __restrict__ dg,
                      float* __restrict__ ma, float* __restrict__ da) {
    int g = blockIdx.x;
    int s0 = starts[g], s1 = starts[g + 1];
    int tid = threadIdx.x, lane = tid & 63, w = tid >> 6;
    __shared__ float red[8];
    float lmg = -3.0e38f, lma = -3.0e38f;
    for (int i = s0 + tid; i < s1; i += 256) {
        lmg = fmaxf(lmg, gs[i]); lma = fmaxf(lma, as_[i]);
    }
    for (int o = 32; o; o >>= 1) {
        lmg = fmaxf(lmg, __shfl_xor(lmg, o));
        lma = fmaxf(lma, __shfl_xor(lma, o));
    }
    if (lane == 0) { red[w] = lmg; red[4 + w] = lma; }
    __syncthreads();
    float Mg = fmaxf(fmaxf(red[0], red[1]), fmaxf(red[2], red[3]));
    float Ma = fmaxf(fmaxf(red[4], red[5]), fmaxf(red[6], red[7]));
    __syncthreads();
    float sgv = 0.f, sav = 0.f;
    for (int i = s0 + tid; i < s1; i += 256) {
        sgv += expf(gs[i] - Mg); sav += expf(as_[i] - Ma);
    }
    for (int o = 32; o; o >>= 1) { sgv += __shfl_xor(sgv, o); sav += __shfl_xor(sav, o); }
    if (lane == 0) { red[w] = sgv; red[4 + w] = sav; }
    __syncthreads();
    if (tid == 0) {
        mg[g] = Mg; ma[g] = Ma;
        dg[g] = red[0] + red[1] + red[2] + red[3];
        da[g] = red[4] + red[5] + red[6] + red[7];
    }
}

// ---------------- normalize: gate weights + attention output ----------------
__global__ void k_final(const float* __restrict__ gs, const float* __restrict__ as_,
                        const int* __restrict__ batch,
                        const float* __restrict__ mg, const float* __restrict__ dg,
                        const float* __restrict__ ma, const float* __restrict__ da,
                        float* __restrict__ gate, float* __restrict__ attn) {
    int stride = gridDim.x * blockDim.x;
    for (int i = blockIdx.x * blockDim.x + threadIdx.x; i < NN; i += stride) {
        int b = batch[i];
        gate[i] = expf(gs[i] - mg[b]) / (dg[b] + 1e-16f);
        attn[i] = expf(as_[i] - ma[b]) / (da[b] + 1e-16f);
    }
}

// ---------------- graph embedding: segment-weighted sum of xt ----------------
// xt position p maps to col: s2=p>>5, j=p&1, l16=(p>>1)&15 -> col = s2*32+j*16+l16
__global__ void k_emb(const u16* __restrict__ xt, const float* __restrict__ gate,
                      const int* __restrict__ starts, float* __restrict__ out) {
    int g = blockIdx.y;
    int part = blockIdx.x;
    int s0 = starts[g], s1 = starts[g + 1];
    int len = s1 - s0;
    int p0 = s0 + (len * part) / 4, p1 = s0 + (len * (part + 1)) / 4;
    int c2 = threadIdx.x;
    int col0 = (c2 >> 4) * 32 + (c2 & 15);   // ushort2 -> cols col0, col0+16
    float a0 = 0.f, a1 = 0.f;
    for (int n = p0; n < p1; ++n) {
        float gn = gate[n];
        ushort2 u = reinterpret_cast<const ushort2*>(xt + (size_t)n * 512)[c2];
        a0 += gn * bf2f(u.x);
        a1 += gn * bf2f(u.y);
    }
    atomicAdd(&out[g * 512 + col0], a0);
    atomicAdd(&out[g * 512 + col0 + 16], a1);
}

extern "C" void kernel_launch(void* const* d_in, const int* in_sizes, int n_in,
                              void* d_out, int out_size, void* d_ws, size_t ws_size,
                              hipStream_t stream) {
    const float* x       = (const float*)d_in[0];
    const int*   batch   = (const int*)d_in[1];
    const float* ga_g_w1 = (const float*)d_in[2];
    const float* ga_g_b1 = (const float*)d_in[3];
    const float* ga_g_w2 = (const float*)d_in[4];
    const float* ga_g_b2 = (const float*)d_in[5];
    const float* ga_n_w  = (const float*)d_in[6];
    const float* ga_n_b  = (const float*)d_in[7];
    const float* g_w1    = (const float*)d_in[8];
    const float* g_b1    = (const float*)d_in[9];
    const float* g_w2    = (const float*)d_in[10];
    const float* g_b2    = (const float*)d_in[11];

    float* out_emb = (float*)d_out;                  // (512, 512)
    float* out_att = out_emb + GG * HH;              // (100000,)

    char* p = (char*)d_ws;
    size_t off = 0;
    auto alloc = [&](size_t bytes) -> char* {
        char* q = p + off;
        off += (bytes + 255) & ~(size_t)255;
        return q;
    };
    u16*    xt    = (u16*)   alloc((size_t)XTROWS * HH * 2);  // relu(x@ga_n_w+b) bf16 (padded)
    u16*    WT    = (u16*)   alloc((size_t)NPACK * 512 * 2);  // strip-blocked swizzled W^T bf16
    float2* bwv   = (float2*)alloc((NPACK + 16) * 8);         // (bias, wvec) pairs (+pad)
    float*  gs    = (float*) alloc((size_t)NN * 4);
    float*  as_   = (float*) alloc((size_t)NN * 4);
    float*  gate  = (float*) alloc((size_t)NN * 4);
    float*  mg    = (float*) alloc(GG * 4);
    float*  dg    = (float*) alloc(GG * 4);
    float*  ma    = (float*) alloc(GG * 4);
    float*  da    = (float*) alloc(GG * 4);
    int*    starts= (int*)   alloc((GG + 1) * 4);

    k_prep<<<2560, 256, 0, stream>>>(ga_g_w1, ga_g_b1, ga_g_w2, ga_n_w, ga_n_b,
                                     g_w1, g_b1, g_w2, batch, WT, bwv, out_emb, starts);
    k_gemm<<<782, 256, 0, stream>>>(x, WT, bwv, ga_g_b2, g_b2, xt, gs, as_);
    k_seg<<<GG, 256, 0, stream>>>(gs, as_, starts, mg, dg, ma, da);
    k_final<<<400, 256, 0, stream>>>(gs, as_, batch, mg, dg, ma, da, gate, out_att);
    k_emb<<<dim3(4, GG), 256, 0, stream>>>(xt, gate, starts, out_emb);
}

// Round 4
// 522.162 us; speedup vs baseline: 1.5772x; 1.5772x over previous
//
#include <hip/hip_runtime.h>

#define NN 100000
#define HH 512
#define GG 512
#define NPACK 1280
#define NSTRIP 80
#define SB 16384               // strip bytes: 16 cols x 512 k x 2B
#define XTROWS (NN + 128)      // pad rows so tail-block xt stores are unguarded (uniform vmcnt)

typedef unsigned short u16;
typedef unsigned int u32;
typedef __bf16 bf16x8 __attribute__((ext_vector_type(8)));
typedef unsigned short u16x8 __attribute__((ext_vector_type(8)));
typedef float f32x4 __attribute__((ext_vector_type(4)));
typedef __attribute__((address_space(1))) void gvoid_t;
typedef __attribute__((address_space(3))) void lvoid_t;

__device__ __forceinline__ u16 f2bf(float f) {
    unsigned u = __float_as_uint(f);
    unsigned r = u + 0x7FFFu + ((u >> 16) & 1u);   // RNE
    return (u16)(r >> 16);
}
__device__ __forceinline__ float bf2f(u16 b) {
    return __uint_as_float(((unsigned)b) << 16);
}

// ---------------- prep: 16-col-strip-blocked + XOR-swizzled W^T bf16 -----------
// packed col n: [0,256)=ga_g_w1 ; [256,768)=ga_n_w ; [768,1280)=g_w1
// WT layout: strip s=n>>4, nl=n&15. byte = s*SB + nl*1024 + ((ck ^ nl)<<4) + k3*2
//   (ck=k>>3, k3=k&7). Linear global_load_lds staging lands this swizzled in LDS;
//   ds_read_b128 fragment reads are then bank-conflict-free (verified 0 in r2/r3).
// bwv[n] = (bias[n], wvec[n]) float2; k_gemm copies it into LDS once.
__global__ void k_prep(const float* __restrict__ gw1, const float* __restrict__ gb1,
                       const float* __restrict__ gw2v,
                       const float* __restrict__ nw, const float* __restrict__ nb,
                       const float* __restrict__ aw1, const float* __restrict__ ab1,
                       const float* __restrict__ aw2, const int* __restrict__ batch,
                       u16* __restrict__ WT, float2* __restrict__ bwv,
                       int* __restrict__ starts) {
    int idx = blockIdx.x * blockDim.x + threadIdx.x;
    int stride = gridDim.x * blockDim.x;
    for (int i = idx; i < NPACK * 512; i += stride) {
        int n = i >> 9, k = i & 511;
        float v;
        if (n < 256)      v = gw1[k * 256 + n];
        else if (n < 768) v = nw[k * 512 + (n - 256)];
        else              v = aw1[k * 512 + (n - 768)];
        int s = n >> 4, nl = n & 15;
        int ck = k >> 3, k3 = k & 7;
        size_t byte = (size_t)s * SB + nl * 1024 + ((size_t)(ck ^ nl) << 4) + k3 * 2;
        *(u16*)((char*)WT + byte) = f2bf(v);
    }
    for (int n = idx; n < NPACK; n += stride) {
        float bi, wv;
        if (n < 256)      { bi = gb1[n];       wv = gw2v[n]; }
        else if (n < 768) { bi = nb[n - 256];  wv = 0.f; }
        else {
            bi = ab1[n - 768];
            float s = 0.f;
            for (int h = 0; h < 8; ++h) s += aw2[(n - 768) * 8 + h];
            wv = s * 0.125f;
        }
        bwv[n] = make_float2(bi, wv);
    }
    for (int g = idx; g <= GG; g += stride) {
        if (g == GG) { starts[GG] = NN; continue; }
        int lo = 0, hi = NN;
        while (lo < hi) { int mid = (lo + hi) >> 1; if (batch[mid] < g) lo = mid + 1; else hi = mid; }
        starts[g] = lo;
    }
}

// ---------------- fused GEMM, strip-pipelined ----------------------------------
// block = 128 rows as 4 waves x 32 rows (a_reg 128 VGPR). 1280 cols as 80 strips
// of 16. Per strip: dbuf 16KB LDS stage (4 global_load_lds/thread), raw s_barrier
// + COUNTED vmcnt. launch_bounds(256,2): VGPR cap 256 (r3's (256,3) spilled a_reg
// to scratch, VGPR=84, FETCH +224MB). LDS 42KB/block -> 3 blocks/CU if compiler
// lands <=170 VGPR (3 waves/SIMD); worst case 2 waves/SIMD == r2 perf.
// ONLY VMEM in loop: STAGE + xt/gs stores (bias/wvec read from LDS).
// nt 0-15: gate | 16-47: xt (even: stash, odd: ushort2 store) | 48-79: att.
__global__ __launch_bounds__(256, 2)
void k_gemm(const float* __restrict__ X, const u16* __restrict__ B,
            const float2* __restrict__ bwv,
            const float* __restrict__ gb2, const float* __restrict__ ab2,
            u16* __restrict__ xt, float* __restrict__ gs, float* __restrict__ as_) {
    __shared__ __align__(16) char ldsB[2 * SB];
    __shared__ __align__(8) float2 bwv_lds[NPACK];

    const int tid = threadIdx.x;
    const int lane = tid & 63;
    const int w = tid >> 6;                  // wave -> rows [w*32, w*32+32)
    const int m0 = blockIdx.x * 128;
    const int l16 = lane & 15, kq = lane >> 4;

#define STAGE(s, bsel) do {                                                          \
    const char* _src = (const char*)B + (size_t)(s) * SB + tid * 16;                 \
    char* _dst = ldsB + (bsel) * SB + tid * 16;                                      \
    _Pragma("unroll")                                                                \
    for (int _t = 0; _t < 4; ++_t)                                                   \
        __builtin_amdgcn_global_load_lds((gvoid_t*)(_src + _t * 4096),               \
                                         (lvoid_t*)(_dst + _t * 4096), 16, 0, 0);    \
} while (0)

    STAGE(0, 0);   // strip 0 in flight under bwv copy + A-panel load

    for (int t = tid; t < NPACK; t += 256) bwv_lds[t] = bwv[t];

    float b2 = gb2[0];
    float bb = 0.f;
#pragma unroll
    for (int h = 0; h < 8; ++h) bb += ab2[h];
    bb *= 0.125f;

    __syncthreads();   // bwv_lds visible to all; drains STAGE(0) (pre-A-panel: harmless)

    // ---- A panel: 32 rows/wave, fp32 -> bf16 fragments in registers (128 VGPR) ----
    bf16x8 a_reg[2][16];
#pragma unroll
    for (int i = 0; i < 2; ++i) {
        int row = m0 + w * 32 + i * 16 + l16;
        if (row >= NN) row = NN - 1;
        const float* xp = X + (size_t)row * 512 + kq * 8;
#pragma unroll
        for (int kt = 0; kt < 16; ++kt) {
            float4 f0 = *(const float4*)(xp + kt * 32);
            float4 f1 = *(const float4*)(xp + kt * 32 + 4);
            u16x8 u;
            u[0] = f2bf(f0.x); u[1] = f2bf(f0.y); u[2] = f2bf(f0.z); u[3] = f2bf(f0.w);
            u[4] = f2bf(f1.x); u[5] = f2bf(f1.y); u[6] = f2bf(f1.z); u[7] = f2bf(f1.w);
            a_reg[i][kt] = __builtin_bit_cast(bf16x8, u);
        }
    }

    float s_[2][4];              // gate phase (nt<16) then att phase (nt>=48)
#pragma unroll
    for (int i = 0; i < 2; ++i)
#pragma unroll
        for (int r = 0; r < 4; ++r) s_[i][r] = 0.f;
    u32 stash[4];                // even-xt-strip bf16 halves (2 u16 per u32)

    for (int nt = 0; nt < NSTRIP; ++nt) {
        const int cur = nt & 1;
        if (nt + 1 < NSTRIP) STAGE(nt + 1, cur ^ 1);

        // Counted waits. Queue (oldest->newest): STAGE(nt)=4,
        // [stores(nt-1)=8 iff nt-1 odd-xt i.e. nt in {18..48} even], STAGE(nt+1)=4.
        // Drain exactly STAGE(nt)+stores; keep the prefetch in flight.
        if (nt == NSTRIP - 1)
            asm volatile("s_waitcnt vmcnt(0)" ::: "memory");
        else if (nt >= 18 && nt <= 48 && !(nt & 1))
            asm volatile("s_waitcnt vmcnt(12)" ::: "memory");
        else
            asm volatile("s_waitcnt vmcnt(4)" ::: "memory");
        __builtin_amdgcn_s_barrier();
        __builtin_amdgcn_sched_barrier(0);   // rule #18: no ds_read hoists above barrier

        f32x4 acc[2];
        acc[0] = {0.f, 0.f, 0.f, 0.f};
        acc[1] = {0.f, 0.f, 0.f, 0.f};

        // b-frag: col n = l16, k-chunk ck = kt*4+kq, byte = l16*1024 + ((ck^l16)<<4)
        const char* bbase = ldsB + cur * SB + l16 * 1024;
        __builtin_amdgcn_s_setprio(1);
#pragma unroll
        for (int kt = 0; kt < 16; ++kt) {
            int off = ((kt * 4 + kq) ^ l16) << 4;
            bf16x8 b0 = *(const bf16x8*)(bbase + off);
            acc[0] = __builtin_amdgcn_mfma_f32_16x16x32_bf16(a_reg[0][kt], b0, acc[0], 0, 0, 0);
            acc[1] = __builtin_amdgcn_mfma_f32_16x16x32_bf16(a_reg[1][kt], b0, acc[1], 0, 0, 0);
        }
        __builtin_amdgcn_s_setprio(0);
        __builtin_amdgcn_s_barrier();   // all waves done reading buf[cur] before restage

        // ---- epilogue. C/D: col = lane&15, row = kq*4 + reg [m89] ----
        float2 bw = bwv_lds[nt * 16 + l16];
        if (nt < 16) {
#pragma unroll
            for (int i = 0; i < 2; ++i)
#pragma unroll
                for (int r = 0; r < 4; ++r)
                    s_[i][r] += fmaxf(acc[i][r] + bw.x, 0.f) * bw.y;
            if (nt == 15) {   // gate scores complete: reduce 16 col-lanes, write, reset
#pragma unroll
                for (int i = 0; i < 2; ++i)
#pragma unroll
                    for (int r = 0; r < 4; ++r) {
                        float pg = s_[i][r];
                        pg += __shfl_xor(pg, 1); pg += __shfl_xor(pg, 2);
                        pg += __shfl_xor(pg, 4); pg += __shfl_xor(pg, 8);
                        int rg = m0 + w * 32 + i * 16 + kq * 4 + r;
                        if (l16 == 0 && rg < NN) gs[rg] = pg + b2;
                        s_[i][r] = 0.f;
                    }
            }
        } else if (nt < 48) {
            const int sx = nt - 16;
            if (!(sx & 1)) {      // even: stash bf16 (no stores -> vmcnt unaffected)
#pragma unroll
                for (int i = 0; i < 2; ++i)
#pragma unroll
                    for (int rp = 0; rp < 2; ++rp) {
                        u32 lo = f2bf(fmaxf(acc[i][rp * 2]     + bw.x, 0.f));
                        u32 hi = f2bf(fmaxf(acc[i][rp * 2 + 1] + bw.x, 0.f));
                        stash[i * 2 + rp] = lo | (hi << 16);
                    }
            } else {              // odd: pair with stash -> ushort2 layout (as r2/r3)
                const int s2 = sx >> 1;
#pragma unroll
                for (int i = 0; i < 2; ++i)
#pragma unroll
                    for (int r = 0; r < 4; ++r) {
                        int rg = m0 + w * 32 + i * 16 + kq * 4 + r;   // < XTROWS always
                        ushort2 st;
                        st.x = (u16)(stash[i * 2 + (r >> 1)] >> ((r & 1) * 16));
                        st.y = f2bf(fmaxf(acc[i][r] + bw.x, 0.f));
                        *(ushort2*)(xt + (size_t)rg * 512 + s2 * 32 + l16 * 2) = st;
                    }
            }
        } else {
#pragma unroll
            for (int i = 0; i < 2; ++i)
#pragma unroll
                for (int r = 0; r < 4; ++r)
                    s_[i][r] += fmaxf(acc[i][r] + bw.x, 0.f) * bw.y;
        }
    }
#undef STAGE

    // ---- att scores: reduce over 16 col-lanes, coalesced write, no atomics ----
#pragma unroll
    for (int i = 0; i < 2; ++i)
#pragma unroll
        for (int r = 0; r < 4; ++r) {
            float pa = s_[i][r];
            pa += __shfl_xor(pa, 1); pa += __shfl_xor(pa, 2);
            pa += __shfl_xor(pa, 4); pa += __shfl_xor(pa, 8);
            int rg = m0 + w * 32 + i * 16 + kq * 4 + r;
            if (l16 == 0 && rg < NN) as_[rg] = pa + bb;
        }
}

// ------- fused per-graph softmax: max + exp-sum + normalize (gate & attn) ------
__global__ void k_seg(const float* __restrict__ gs, const float* __restrict__ as_,
                      const int* __restrict__ starts,
                      float* __restrict__ gate, float* __restrict__ attn) {
    int g = blockIdx.x;
    int s0 = starts[g], s1 = starts[g + 1];
    int tid = threadIdx.x, lane = tid & 63, w = tid >> 6;
    __shared__ float red[8];
    float lmg = -3.0e38f, lma = -3.0e38f;
    for (int i = s0 + tid; i < s1; i += 256) {
        lmg = fmaxf(lmg, gs[i]); lma = fmaxf(lma, as_[i]);
    }
    for (int o = 32; o; o >>= 1) {
        lmg = fmaxf(lmg, __shfl_xor(lmg, o));
        lma = fmaxf(lma, __shfl_xor(lma, o));
    }
    if (lane == 0) { red[w] = lmg; red[4 + w] = lma; }
    __syncthreads();
    float Mg = fmaxf(fmaxf(red[0], red[1]), fmaxf(red[2], red[3]));
    float Ma = fmaxf(fmaxf(red[4], red[5]), fmaxf(red[6], red[7]));
    __syncthreads();
    float sgv = 0.f, sav = 0.f;
    for (int i = s0 + tid; i < s1; i += 256) {
        sgv += expf(gs[i] - Mg); sav += expf(as_[i] - Ma);
    }
    for (int o = 32; o; o >>= 1) { sgv += __shfl_xor(sgv, o); sav += __shfl_xor(sav, o); }
    if (lane == 0) { red[w] = sgv; red[4 + w] = sav; }
    __syncthreads();
    float Dg = red[0] + red[1] + red[2] + red[3] + 1e-16f;
    float Da = red[4] + red[5] + red[6] + red[7] + 1e-16f;
    for (int i = s0 + tid; i < s1; i += 256) {
        gate[i] = expf(gs[i] - Mg) / Dg;
        attn[i] = expf(as_[i] - Ma) / Da;
    }
}

// ---------------- graph embedding: one block per graph, NO atomics -------------
// xt position p maps to col: s2=p>>5, j=p&1, l16=(p>>1)&15 -> col = s2*32+j*16+l16
// thread c2 reads ushort2 -> cols col0, col0+16. 4-deep unroll for MLP.
__global__ __launch_bounds__(256)
void k_emb(const u16* __restrict__ xt, const float* __restrict__ gate,
           const int* __restrict__ starts, float* __restrict__ out) {
    int g = blockIdx.x;
    int s0 = starts[g], s1 = starts[g + 1];
    int c2 = threadIdx.x;
    int col0 = (c2 >> 4) * 32 + (c2 & 15);
    float a0 = 0.f, a1 = 0.f;
    int n = s0;
    for (; n + 4 <= s1; n += 4) {
        ushort2 u0 = reinterpret_cast<const ushort2*>(xt + (size_t)(n + 0) * 512)[c2];
        ushort2 u1 = reinterpret_cast<const ushort2*>(xt + (size_t)(n + 1) * 512)[c2];
        ushort2 u2 = reinterpret_cast<const ushort2*>(xt + (size_t)(n + 2) * 512)[c2];
        ushort2 u3 = reinterpret_cast<const ushort2*>(xt + (size_t)(n + 3) * 512)[c2];
        float g0 = gate[n], g1 = gate[n + 1], g2 = gate[n + 2], g3 = gate[n + 3];
        a0 += g0 * bf2f(u0.x); a1 += g0 * bf2f(u0.y);
        a0 += g1 * bf2f(u1.x); a1 += g1 * bf2f(u1.y);
        a0 += g2 * bf2f(u2.x); a1 += g2 * bf2f(u2.y);
        a0 += g3 * bf2f(u3.x); a1 += g3 * bf2f(u3.y);
    }
    for (; n < s1; ++n) {
        float gn = gate[n];
        ushort2 u = reinterpret_cast<const ushort2*>(xt + (size_t)n * 512)[c2];
        a0 += gn * bf2f(u.x);
        a1 += gn * bf2f(u.y);
    }
    out[g * 512 + col0] = a0;          // every (g,col) written: no pre-zero needed
    out[g * 512 + col0 + 16] = a1;
}

extern "C" void kernel_launch(void* const* d_in, const int* in_sizes, int n_in,
                              void* d_out, int out_size, void* d_ws, size_t ws_size,
                              hipStream_t stream) {
    const float* x       = (const float*)d_in[0];
    const int*   batch   = (const int*)d_in[1];
    const float* ga_g_w1 = (const float*)d_in[2];
    const float* ga_g_b1 = (const float*)d_in[3];
    const float* ga_g_w2 = (const float*)d_in[4];
    const float* ga_g_b2 = (const float*)d_in[5];
    const float* ga_n_w  = (const float*)d_in[6];
    const float* ga_n_b  = (const float*)d_in[7];
    const float* g_w1    = (const float*)d_in[8];
    const float* g_b1    = (const float*)d_in[9];
    const float* g_w2    = (const float*)d_in[10];
    const float* g_b2    = (const float*)d_in[11];

    float* out_emb = (float*)d_out;                  // (512, 512)
    float* out_att = out_emb + GG * HH;              // (100000,)

    char* p = (char*)d_ws;
    size_t off = 0;
    auto alloc = [&](size_t bytes) -> char* {
        char* q = p + off;
        off += (bytes + 255) & ~(size_t)255;
        return q;
    };
    u16*    xt    = (u16*)   alloc((size_t)XTROWS * HH * 2);  // relu(x@ga_n_w+b) bf16 (padded)
    u16*    WT    = (u16*)   alloc((size_t)NPACK * 512 * 2);  // strip-blocked swizzled W^T bf16
    float2* bwv   = (float2*)alloc(NPACK * 8);                // (bias, wvec) pairs
    float*  gs    = (float*) alloc((size_t)NN * 4);
    float*  as_   = (float*) alloc((size_t)NN * 4);
    float*  gate  = (float*) alloc((size_t)NN * 4);
    int*    starts= (int*)   alloc((GG + 1) * 4);

    k_prep<<<2560, 256, 0, stream>>>(ga_g_w1, ga_g_b1, ga_g_w2, ga_n_w, ga_n_b,
                                     g_w1, g_b1, g_w2, batch, WT, bwv, starts);
    k_gemm<<<782, 256, 0, stream>>>(x, WT, bwv, ga_g_b2, g_b2, xt, gs, as_);
    k_seg<<<GG, 256, 0, stream>>>(gs, as_, starts, gate, out_att);
    k_emb<<<GG, 256, 0, stream>>>(xt, gate, starts, out_emb);
}

// Round 6
// 487.019 us; speedup vs baseline: 1.6910x; 1.0722x over previous
//
#include <hip/hip_runtime.h>

#define NN 100000
#define HH 512
#define GG 512
#define NPACK 1280
#define NSTRIP 40
#define SB 32768               // gemm strip: 32 cols x 512 k x 2B (= 2 16-col substrips)
#define SB16 16384             // WT global blocking: 16-col strips
#define XTROWS (NN + 128)      // pad rows so tail-block xt stores are unguarded

typedef unsigned short u16;
typedef unsigned int u32;
typedef __bf16 bf16x8 __attribute__((ext_vector_type(8)));
typedef unsigned short u16x8 __attribute__((ext_vector_type(8)));
typedef float f32x4 __attribute__((ext_vector_type(4)));
typedef __attribute__((address_space(1))) void gvoid_t;
typedef __attribute__((address_space(3))) void lvoid_t;

__device__ __forceinline__ u16 f2bf(float f) {
    unsigned u = __float_as_uint(f);
    unsigned r = u + 0x7FFFu + ((u >> 16) & 1u);   // RNE
    return (u16)(r >> 16);
}
__device__ __forceinline__ float bf2f(u16 b) {
    return __uint_as_float(((unsigned)b) << 16);
}

// ---------------- prep: tiled transpose into 16-col-strip swizzled W^T ---------
// packed col n: [0,256)=ga_g_w1 ; [256,768)=ga_n_w ; [768,1280)=g_w1
// WT byte for (n,k): s=n>>4, nl=n&15, ck=k>>3, k3=k&7:
//   s*SB16 + nl*1024 + ((ck^nl)<<4) + k3*2
// Blocks 0..159: 64n x 64k tile each — coalesced float4 reads, LDS transpose,
// 16-B aligned swizzled writes. Block 160: bwv pairs + segment starts.
__global__ __launch_bounds__(256)
void k_prep(const float* __restrict__ gw1, const float* __restrict__ gb1,
            const float* __restrict__ gw2v,
            const float* __restrict__ nw, const float* __restrict__ nbias,
            const float* __restrict__ aw1, const float* __restrict__ ab1,
            const float* __restrict__ aw2, const int* __restrict__ batch,
            u16* __restrict__ WT, float2* __restrict__ bwv,
            int* __restrict__ starts) {
    __shared__ u16 lt[64][80];           // [n_local][k_local], row stride 160 B (16-B mult)
    const int b = blockIdx.x, tid = threadIdx.x;
    if (b < 160) {
        const int bn = b >> 3, bk = b & 7;
        const int N0 = bn * 64, K0 = bk * 64;
        const float* src; int LD, nb0;
        if (N0 < 256)      { src = gw1; LD = 256; nb0 = N0; }
        else if (N0 < 768) { src = nw;  LD = 512; nb0 = N0 - 256; }
        else               { src = aw1; LD = 512; nb0 = N0 - 768; }
        const int kr = tid >> 2, q = tid & 3;            // row K0+kr, n-quarter q
        const float* sp = src + (size_t)(K0 + kr) * LD + nb0 + q * 16;
#pragma unroll
        for (int jj = 0; jj < 4; ++jj) {
            float4 f = *(const float4*)(sp + jj * 4);
            lt[q * 16 + jj * 4 + 0][kr] = f2bf(f.x);
            lt[q * 16 + jj * 4 + 1][kr] = f2bf(f.y);
            lt[q * 16 + jj * 4 + 2][kr] = f2bf(f.z);
            lt[q * 16 + jj * 4 + 3][kr] = f2bf(f.w);
        }
        __syncthreads();
        const int nlcl = tid >> 2, c2 = tid & 3;
        const int n = N0 + nlcl;
        const int s = n >> 4, nl = n & 15;
#pragma unroll
        for (int cc = 0; cc < 2; ++cc) {
            int c = c2 * 2 + cc;                          // 16-B chunk (8 k-elems)
            int ckb = (K0 >> 3) + c;
            size_t byte = (size_t)s * SB16 + nl * 1024 + ((size_t)(ckb ^ nl) << 4);
            *(u16x8*)((char*)WT + byte) = *(const u16x8*)(&lt[nlcl][c * 8]);
        }
    } else {
        for (int n = tid; n < NPACK; n += 256) {
            float bi, wv;
            if (n < 256)      { bi = gb1[n];        wv = gw2v[n]; }
            else if (n < 768) { bi = nbias[n - 256]; wv = 0.f; }
            else {
                bi = ab1[n - 768];
                float s = 0.f;
                for (int h = 0; h < 8; ++h) s += aw2[(n - 768) * 8 + h];
                wv = s * 0.125f;
            }
            bwv[n] = make_float2(bi, wv);
        }
        for (int g = tid; g <= GG; g += 256) {
            if (g == GG) { starts[GG] = NN; continue; }
            int lo = 0, hi = NN;
            while (lo < hi) { int mid = (lo + hi) >> 1; if (batch[mid] < g) lo = mid + 1; else hi = mid; }
            starts[g] = lo;
        }
    }
}

// ---------------- fused GEMM: 32-col strips, SINGLE barrier per strip ----------
// block = 128 rows as 4 waves x 32 rows (a_reg 128 VGPR, 4 acc chains). 40 strips.
// Per strip: wait(strip nt per-wave) -> barrier (strip nt visible AND all waves
// done reading buf[cur^1]) -> STAGE(nt+1) into cur^1 (race-free) -> 64 MFMA ->
// epilogue. Counted vmcnt: stores from strip nt-1 stay in flight (vmcnt(8) on
// nt in [8,24], else 0 -- no loop VMEM loads since bias/wvec live in LDS).
// nt 0-7: gate | 8-23: xt ushort2 stores | 24-39: att score.
__global__ __launch_bounds__(256, 2)
void k_gemm(const float* __restrict__ X, const u16* __restrict__ B,
            const float2* __restrict__ bwv,
            const float* __restrict__ gb2, const float* __restrict__ ab2,
            u16* __restrict__ xt, float* __restrict__ gs, float* __restrict__ as_) {
    __shared__ __align__(16) char ldsB[2 * SB];
    __shared__ __align__(8) float2 bwv_lds[NPACK];

    const int tid = threadIdx.x;
    const int lane = tid & 63;
    const int w = tid >> 6;                  // wave -> rows [w*32, w*32+32)
    const int m0 = blockIdx.x * 128;
    const int l16 = lane & 15, kq = lane >> 4;

#define STAGE(s, bsel) do {                                                          \
    const char* _src = (const char*)B + (size_t)(s) * SB + tid * 16;                 \
    char* _dst = ldsB + (bsel) * SB + tid * 16;                                      \
    _Pragma("unroll")                                                                \
    for (int _t = 0; _t < 8; ++_t)                                                   \
        __builtin_amdgcn_global_load_lds((gvoid_t*)(_src + _t * 4096),               \
                                         (lvoid_t*)(_dst + _t * 4096), 16, 0, 0);    \
} while (0)

    STAGE(0, 0);   // strip 0 in flight under bwv copy + A-panel load

    for (int t = tid; t < NPACK; t += 256) bwv_lds[t] = bwv[t];

    float b2 = gb2[0];
    float bb = 0.f;
#pragma unroll
    for (int h = 0; h < 8; ++h) bb += ab2[h];
    bb *= 0.125f;

    // ---- A panel: 32 rows/wave, fp32 -> bf16 fragments in registers (128 VGPR) ----
    bf16x8 a_reg[2][16];
#pragma unroll
    for (int i = 0; i < 2; ++i) {
        int row = m0 + w * 32 + i * 16 + l16;
        if (row >= NN) row = NN - 1;
        const float* xp = X + (size_t)row * 512 + kq * 8;
#pragma unroll
        for (int kt = 0; kt < 16; ++kt) {
            float4 f0 = *(const float4*)(xp + kt * 32);
            float4 f1 = *(const float4*)(xp + kt * 32 + 4);
            u16x8 u;
            u[0] = f2bf(f0.x); u[1] = f2bf(f0.y); u[2] = f2bf(f0.z); u[3] = f2bf(f0.w);
            u[4] = f2bf(f1.x); u[5] = f2bf(f1.y); u[6] = f2bf(f1.z); u[7] = f2bf(f1.w);
            a_reg[i][kt] = __builtin_bit_cast(bf16x8, u);
        }
    }

    float s_[2][4];              // gate accumulator (nt<8) then att accumulator (nt>=24)
#pragma unroll
    for (int i = 0; i < 2; ++i)
#pragma unroll
        for (int r = 0; r < 4; ++r) s_[i][r] = 0.f;

    __syncthreads();   // drains STAGE(0) + bwv/A loads; bwv_lds visible

    for (int nt = 0; nt < NSTRIP; ++nt) {
        const int cur = nt & 1;

        // Per-wave drain of strip nt (except right after __syncthreads at nt=0).
        // Queue (oldest->newest): STAGE(nt)=8, [stores(nt-1)=8 iff nt in 8..24].
        if (nt >= 8 && nt <= 24) asm volatile("s_waitcnt vmcnt(8)" ::: "memory");
        else                     asm volatile("s_waitcnt vmcnt(0)" ::: "memory");
        __builtin_amdgcn_s_barrier();        // all portions of strip nt in LDS;
        __builtin_amdgcn_sched_barrier(0);   // all waves done reading buf[cur^1]

        if (nt + 1 < NSTRIP) STAGE(nt + 1, cur ^ 1);   // safe: see barrier invariant

        f32x4 acc[2][2];
#pragma unroll
        for (int i = 0; i < 2; ++i) { acc[i][0] = {0.f,0.f,0.f,0.f}; acc[i][1] = {0.f,0.f,0.f,0.f}; }

        // b-frag: substrip j, col n = j*16+l16, k-chunk ck = kt*4+kq,
        // byte = j*16384 + l16*1024 + ((ck^l16)<<4)
        const char* bbase = ldsB + cur * SB + l16 * 1024;
        __builtin_amdgcn_s_setprio(1);
#pragma unroll
        for (int kt = 0; kt < 16; ++kt) {
            int off = ((kt * 4 + kq) ^ l16) << 4;
            bf16x8 b0 = *(const bf16x8*)(bbase + off);
            bf16x8 b1 = *(const bf16x8*)(bbase + 16384 + off);
#pragma unroll
            for (int i = 0; i < 2; ++i) {
                acc[i][0] = __builtin_amdgcn_mfma_f32_16x16x32_bf16(a_reg[i][kt], b0, acc[i][0], 0, 0, 0);
                acc[i][1] = __builtin_amdgcn_mfma_f32_16x16x32_bf16(a_reg[i][kt], b1, acc[i][1], 0, 0, 0);
            }
        }
        __builtin_amdgcn_s_setprio(0);

        // ---- epilogue. C/D: col = lane&15, row = kq*4 + reg [m89] ----
        float2 bw0 = bwv_lds[nt * 32 + l16];
        float2 bw1 = bwv_lds[nt * 32 + 16 + l16];
        if (nt >= 8 && nt < 24) {
            const int sx = nt - 8;     // xt position p = sx*32 + l16*2 + j (k_post remaps)
#pragma unroll
            for (int i = 0; i < 2; ++i)
#pragma unroll
                for (int r = 0; r < 4; ++r) {
                    int rg = m0 + w * 32 + i * 16 + kq * 4 + r;   // < XTROWS always
                    ushort2 st;
                    st.x = f2bf(fmaxf(acc[i][0][r] + bw0.x, 0.f));
                    st.y = f2bf(fmaxf(acc[i][1][r] + bw1.x, 0.f));
                    *(ushort2*)(xt + (size_t)rg * 512 + sx * 32 + l16 * 2) = st;
                }
        } else {
#pragma unroll
            for (int i = 0; i < 2; ++i)
#pragma unroll
                for (int r = 0; r < 4; ++r)
                    s_[i][r] += fmaxf(acc[i][0][r] + bw0.x, 0.f) * bw0.y
                              + fmaxf(acc[i][1][r] + bw1.x, 0.f) * bw1.y;
            if (nt == 7) {   // gate scores complete: reduce 16 col-lanes, write, reset
#pragma unroll
                for (int i = 0; i < 2; ++i)
#pragma unroll
                    for (int r = 0; r < 4; ++r) {
                        float pg = s_[i][r];
                        pg += __shfl_xor(pg, 1); pg += __shfl_xor(pg, 2);
                        pg += __shfl_xor(pg, 4); pg += __shfl_xor(pg, 8);
                        int rg = m0 + w * 32 + i * 16 + kq * 4 + r;
                        if (l16 == 0 && rg < NN) gs[rg] = pg + b2;
                        s_[i][r] = 0.f;
                    }
            }
        }
    }
#undef STAGE

    // ---- att scores: reduce over 16 col-lanes, coalesced write, no atomics ----
#pragma unroll
    for (int i = 0; i < 2; ++i)
#pragma unroll
        for (int r = 0; r < 4; ++r) {
            float pa = s_[i][r];
            pa += __shfl_xor(pa, 1); pa += __shfl_xor(pa, 2);
            pa += __shfl_xor(pa, 4); pa += __shfl_xor(pa, 8);
            int rg = m0 + w * 32 + i * 16 + kq * 4 + r;
            if (l16 == 0 && rg < NN) as_[rg] = pa + bb;
        }
}

// --------- fused post: segment softmax (gate+attn) + weighted embedding -------
// One block per graph. Pass1 max, pass2 expsum, pass3 chunked: gate chunk into
// LDS (+ attn global write), then all threads stream xt rows with gbuf broadcast.
// xt position p maps to col: s2=p>>5, j=p&1, l16=(p>>1)&15 -> col = s2*32+j*16+l16
__global__ __launch_bounds__(256)
void k_post(const float* __restrict__ gs, const float* __restrict__ as_,
            const u16* __restrict__ xt, const int* __restrict__ starts,
            float* __restrict__ out_emb, float* __restrict__ out_att) {
    const int g = blockIdx.x;
    const int s0 = starts[g], s1 = starts[g + 1];
    const int tid = threadIdx.x, lane = tid & 63, w = tid >> 6;
    __shared__ float red[8];
    __shared__ float gbuf[1024];

    float lmg = -3.0e38f, lma = -3.0e38f;
    for (int i = s0 + tid; i < s1; i += 256) {
        lmg = fmaxf(lmg, gs[i]); lma = fmaxf(lma, as_[i]);
    }
    for (int o = 32; o; o >>= 1) {
        lmg = fmaxf(lmg, __shfl_xor(lmg, o));
        lma = fmaxf(lma, __shfl_xor(lma, o));
    }
    if (lane == 0) { red[w] = lmg; red[4 + w] = lma; }
    __syncthreads();
    float Mg = fmaxf(fmaxf(red[0], red[1]), fmaxf(red[2], red[3]));
    float Ma = fmaxf(fmaxf(red[4], red[5]), fmaxf(red[6], red[7]));
    __syncthreads();
    float sgv = 0.f, sav = 0.f;
    for (int i = s0 + tid; i < s1; i += 256) {
        sgv += expf(gs[i] - Mg); sav += expf(as_[i] - Ma);
    }
    for (int o = 32; o; o >>= 1) { sgv += __shfl_xor(sgv, o); sav += __shfl_xor(sav, o); }
    if (lane == 0) { red[w] = sgv; red[4 + w] = sav; }
    __syncthreads();
    const float Dg = red[0] + red[1] + red[2] + red[3] + 1e-16f;
    const float Da = red[4] + red[5] + red[6] + red[7] + 1e-16f;

    const int c2 = tid;
    const int col0 = (c2 >> 4) * 32 + (c2 & 15);
    float a0 = 0.f, a1 = 0.f;
    for (int nb = s0; nb < s1; nb += 1024) {
        const int ce = min(s1, nb + 1024);
        __syncthreads();                     // gbuf free for refill
        for (int i = nb + tid; i < ce; i += 256) {
            gbuf[i - nb] = expf(gs[i] - Mg) / Dg;
            out_att[i]   = expf(as_[i] - Ma) / Da;
        }
        __syncthreads();
        const int cl = ce - nb;
        int j = 0;
        for (; j + 4 <= cl; j += 4) {
            const size_t n = (size_t)(nb + j);
            ushort2 u0 = ((const ushort2*)(xt + (n + 0) * 512))[c2];
            ushort2 u1 = ((const ushort2*)(xt + (n + 1) * 512))[c2];
            ushort2 u2 = ((const ushort2*)(xt + (n + 2) * 512))[c2];
            ushort2 u3 = ((const ushort2*)(xt + (n + 3) * 512))[c2];
            float g0 = gbuf[j], g1 = gbuf[j + 1], g2 = gbuf[j + 2], g3 = gbuf[j + 3];
            a0 += g0 * bf2f(u0.x); a1 += g0 * bf2f(u0.y);
            a0 += g1 * bf2f(u1.x); a1 += g1 * bf2f(u1.y);
            a0 += g2 * bf2f(u2.x); a1 += g2 * bf2f(u2.y);
            a0 += g3 * bf2f(u3.x); a1 += g3 * bf2f(u3.y);
        }
        for (; j < cl; ++j) {
            ushort2 u = ((const ushort2*)(xt + (size_t)(nb + j) * 512))[c2];
            float gj = gbuf[j];
            a0 += gj * bf2f(u.x); a1 += gj * bf2f(u.y);
        }
    }
    out_emb[g * 512 + col0] = a0;        // every (g,col) written: no pre-zero needed
    out_emb[g * 512 + col0 + 16] = a1;
}

extern "C" void kernel_launch(void* const* d_in, const int* in_sizes, int n_in,
                              void* d_out, int out_size, void* d_ws, size_t ws_size,
                              hipStream_t stream) {
    const float* x       = (const float*)d_in[0];
    const int*   batch   = (const int*)d_in[1];
    const float* ga_g_w1 = (const float*)d_in[2];
    const float* ga_g_b1 = (const float*)d_in[3];
    const float* ga_g_w2 = (const float*)d_in[4];
    const float* ga_g_b2 = (const float*)d_in[5];
    const float* ga_n_w  = (const float*)d_in[6];
    const float* ga_n_b  = (const float*)d_in[7];
    const float* g_w1    = (const float*)d_in[8];
    const float* g_b1    = (const float*)d_in[9];
    const float* g_w2    = (const float*)d_in[10];
    const float* g_b2    = (const float*)d_in[11];

    float* out_emb = (float*)d_out;                  // (512, 512)
    float* out_att = out_emb + GG * HH;              // (100000,)

    char* p = (char*)d_ws;
    size_t off = 0;
    auto alloc = [&](size_t bytes) -> char* {
        char* q = p + off;
        off += (bytes + 255) & ~(size_t)255;
        return q;
    };
    u16*    xt    = (u16*)   alloc((size_t)XTROWS * HH * 2);  // relu(x@ga_n_w+b) bf16 (padded)
    u16*    WT    = (u16*)   alloc((size_t)NPACK * 512 * 2);  // 16-col-strip swizzled W^T bf16
    float2* bwv   = (float2*)alloc(NPACK * 8);                // (bias, wvec) pairs
    float*  gs    = (float*) alloc((size_t)NN * 4);
    float*  as_   = (float*) alloc((size_t)NN * 4);
    int*    starts= (int*)   alloc((GG + 1) * 4);

    k_prep<<<161, 256, 0, stream>>>(ga_g_w1, ga_g_b1, ga_g_w2, ga_n_w, ga_n_b,
                                    g_w1, g_b1, g_w2, batch, WT, bwv, starts);
    k_gemm<<<782, 256, 0, stream>>>(x, WT, bwv, ga_g_b2, g_b2, xt, gs, as_);
    k_post<<<GG, 256, 0, stream>>>(gs, as_, xt, starts, out_emb, out_att);
}